// Round 2
// baseline (572.413 us; speedup 1.0000x reference)
//
#include <hip/hip_runtime.h>
#include <hip/hip_bf16.h>
#include <stdint.h>

#define T_   8192   // B*S tokens
#define IN_  4096
#define OUT_ 4096
#define GS_  256
#define NG_  16

#define BM 256
#define BN 256
#define BK 128
#define KT (IN_ / BK)     // 32 K-tiles, group = 2 K-tiles
#define GX (OUT_ / BN)    // 16
#define GY (T_ / BM)      // 32

typedef int   v4i __attribute__((ext_vector_type(4)));
typedef float f4  __attribute__((ext_vector_type(4)));

__device__ __forceinline__ void gload16(const void* g, void* l) {
  __builtin_amdgcn_global_load_lds(
      (const __attribute__((address_space(1))) void*)g,
      (__attribute__((address_space(3))) void*)l, 16, 0, 0);
}

// ---------------- per-token dynamic quant ----------------------------------
__global__ __launch_bounds__(256) void quant_kernel(
    const float* __restrict__ x, int8_t* __restrict__ q,
    float* __restrict__ tscale, float* __restrict__ tzp) {
  const int t = blockIdx.x;
  const int tid = threadIdx.x;
  const float* xr = x + (size_t)t * IN_ + tid * 16;
  float vals[16];
  {
    f4 v0 = *(const f4*)(xr);
    f4 v1 = *(const f4*)(xr + 4);
    f4 v2 = *(const f4*)(xr + 8);
    f4 v3 = *(const f4*)(xr + 12);
#pragma unroll
    for (int i = 0; i < 4; ++i) {
      vals[i] = v0[i]; vals[4 + i] = v1[i]; vals[8 + i] = v2[i]; vals[12 + i] = v3[i];
    }
  }
  float mn = 0.f, mx = 0.f;   // ref clamps: min(.,0), max(.,0)
#pragma unroll
  for (int i = 0; i < 16; ++i) { mn = fminf(mn, vals[i]); mx = fmaxf(mx, vals[i]); }
#pragma unroll
  for (int off = 32; off > 0; off >>= 1) {
    mn = fminf(mn, __shfl_xor(mn, off));
    mx = fmaxf(mx, __shfl_xor(mx, off));
  }
  __shared__ float smn[4], smx[4];
  if ((tid & 63) == 0) { smn[tid >> 6] = mn; smx[tid >> 6] = mx; }
  __syncthreads();
  mn = fminf(fminf(smn[0], smn[1]), fminf(smn[2], smn[3]));
  mx = fmaxf(fmaxf(smx[0], smx[1]), fmaxf(smx[2], smx[3]));

  const float eps = 1.1920928955078125e-7f;  // np.finfo(float32).eps
  float scale = fmaxf((mx - mn) / 255.0f, eps);
  float rmn = mn / scale;   // exact divide (zp must be bit-exact)
  float rmx = mx / scale;
  float zp0 = ((-128.0f + rmn) + (127.0f + rmx) > 0.0f) ? (-128.0f - rmn)
                                                        : (127.0f - rmx);
  float zp = fminf(fmaxf(rintf(zp0), -128.0f), 127.0f);
  if (tid == 0) { tscale[t] = scale; tzp[t] = zp; }

  const float inv = 1.0f / scale;  // one exact divide; 16 multiplies below
  v4i packed;
#pragma unroll
  for (int w = 0; w < 4; ++w) {
    int word = 0;
#pragma unroll
    for (int e = 0; e < 4; ++e) {
      float qf = rintf(vals[w * 4 + e] * inv) + zp;
      qf = fminf(fmaxf(qf, -128.0f), 127.0f);
      int qi = (int)qf;
      word |= (qi & 0xff) << (8 * e);
    }
    packed[w] = word;
  }
  *(v4i*)(q + (size_t)t * IN_ + tid * 16) = packed;
}

// ---------------- weight prep: w' = w - z (int8), C1[o] = sum_g s*sum(w') ---
__global__ __launch_bounds__(256) void wprep_kernel(
    const int* __restrict__ w, const float* __restrict__ scales,
    const float* __restrict__ zeros, int8_t* __restrict__ wq,
    float* __restrict__ c1) {
  const int o = blockIdx.x;
  const int tid = threadIdx.x;
  const int g = tid >> 4;  // 16 threads per group of 256 elems
  const int* wr = w + (size_t)o * IN_ + tid * 16;
  const int zi = (int)zeros[o * NG_ + g];
  int ssum = 0;
  v4i packed;
#pragma unroll
  for (int blk = 0; blk < 4; ++blk) {
    v4i ww = *(const v4i*)(wr + blk * 4);
    int word = 0;
#pragma unroll
    for (int e = 0; e < 4; ++e) {
      int wp = ww[e] - zi;   // in [-15,15], fits int8
      ssum += wp;
      word |= (wp & 0xff) << (8 * e);
    }
    packed[blk] = word;
  }
  *(v4i*)(wq + (size_t)o * IN_ + tid * 16) = packed;
  ssum += __shfl_xor(ssum, 1);
  ssum += __shfl_xor(ssum, 2);
  ssum += __shfl_xor(ssum, 4);
  ssum += __shfl_xor(ssum, 8);
  __shared__ float part[NG_];
  if ((tid & 15) == 0) part[g] = scales[o * NG_ + g] * (float)ssum;
  __syncthreads();
  if (tid == 0) {
    float s = 0.f;
#pragma unroll
    for (int i = 0; i < NG_; ++i) s += part[i];
    c1[o] = s;
  }
}

// ---------------- int8 groupwise GEMM, 256x256, 4-phase/kt ------------------
// 8 waves (2M x 4N), wave tile 128x64: LDS reads (8+4) b128 per wave per ks
// vs (4+4) for 64x64 waves -> 17 B/kop, LDS floor ~57us < MFMA floor ~70us.
// Register wall broken by folding int acc -> fp32 EVERY ks (fold is linear in
// the K-partials, same group scale), so acci is single-use (mfma with C=0).
// Pipeline: 4 phases per kt {ds_read subtile | issue 2 stage loads -> barrier
// -> setprio(1) -> 16 MFMA + fold -> setprio(0) -> barrier}; one syncthreads
// per kt whose vmcnt(0) drain is covered (all 8 next-tile loads issued >=2
// phases = ~1300cy earlier > 900cy HBM latency).  No XCD swizzle (round-1
// evidence: it thrashed L2).  XOR-chunk LDS swizzle (T2) as before.
__global__ __launch_bounds__(512, 2) void gemm_kernel(
    const int8_t* __restrict__ q, const int8_t* __restrict__ wq,
    const float* __restrict__ scales, const float* __restrict__ tscale,
    const float* __restrict__ tzp, const float* __restrict__ c1,
    float* __restrict__ out) {
  __shared__ int8_t As[2][BM * BK];   // 2 x 32 KB
  __shared__ int8_t Bs[2][BN * BK];   // 2 x 32 KB
  __shared__ float sSc[NG_ * BN];     // 16 KB   (144 KB total)

  const int tid = threadIdx.x;
  const int lane = tid & 63;
  const int wid = tid >> 6;

  const int R0 = blockIdx.y * BM;
  const int C0 = blockIdx.x * BN;

  // stage this block's scales: sSc[g][col_local]
#pragma unroll
  for (int e = 0; e < 8; ++e) {
    int idx = tid + e * 512;
    int oc = idx >> 4, g = idx & 15;
    sSc[g * BN + oc] = scales[(size_t)(C0 + oc) * NG_ + g];
  }

  // staging: thread covers 16 B; row = tid>>3 (+64 per pass), chunk tid&7
  const int rA = tid >> 3;                       // 0..63
  const int csw = ((tid & 7) ^ (rA & 7)) * 16;   // swizzled global column
  const int8_t* gA = q + (size_t)(R0 + rA) * IN_ + csw;
  const int8_t* gB = wq + (size_t)(C0 + rA) * IN_ + csw;

  const int wm = (wid >> 2) * 128;  // 2 M-waves, 128 rows each
  const int wn = (wid & 3) * 64;    // 4 N-waves, 64 cols each
  const int lm = lane & 15;
  const int quad = lane >> 4;
  const int o0 = (quad ^ (lm & 7)) * 16;   // physical chunk byte off, ks=0

  float accf[8][4][4];
#pragma unroll
  for (int i = 0; i < 8; ++i)
#pragma unroll
    for (int j = 0; j < 4; ++j)
#pragma unroll
      for (int r = 0; r < 4; ++r) accf[i][j][r] = 0.f;

  const v4i zero4 = (v4i){0, 0, 0, 0};

  // prologue: stage tile 0 into buffer 0
#pragma unroll
  for (int i = 0; i < 4; ++i)
    gload16(gA + (size_t)(i * 64) * IN_, &As[0][i * 8192 + tid * 16]);
#pragma unroll
  for (int i = 0; i < 4; ++i)
    gload16(gB + (size_t)(i * 64) * IN_, &Bs[0][i * 8192 + tid * 16]);
  __syncthreads();   // drains vmcnt; also covers sSc writes

  int cur = 0;
  float sj[4];
  for (int kt = 0; kt < KT; ++kt) {
    if ((kt & 1) == 0) {   // new group: hoist this group's 4 col-scales
      const int g = kt >> 1;
#pragma unroll
      for (int j = 0; j < 4; ++j) sj[j] = sSc[g * BN + wn + j * 16 + lm];
    }
    const int8_t* A = As[cur];
    const int8_t* Bb = Bs[cur];
    const size_t koff = (size_t)(kt + 1) * BK;
    v4i af[4], bf[4], t0;

    // ---- phase 1: ks0, M-half 0; issue next-tile A stage ----
#pragma unroll
    for (int j = 0; j < 4; ++j)
      bf[j] = *(const v4i*)&Bb[(wn + j * 16 + lm) * BK + o0];
#pragma unroll
    for (int i = 0; i < 4; ++i)
      af[i] = *(const v4i*)&A[(wm + i * 16 + lm) * BK + o0];
    if (kt + 1 < KT) {
#pragma unroll
      for (int i = 0; i < 4; ++i)
        gload16(gA + koff + (size_t)(i * 64) * IN_,
                &As[cur ^ 1][i * 8192 + tid * 16]);
    }
    __builtin_amdgcn_s_barrier();
    __builtin_amdgcn_s_setprio(1);
#pragma unroll
    for (int i = 0; i < 4; ++i)
#pragma unroll
      for (int j = 0; j < 4; ++j) {
        t0 = __builtin_amdgcn_mfma_i32_16x16x64_i8(af[i], bf[j], zero4, 0, 0, 0);
#pragma unroll
        for (int r = 0; r < 4; ++r) accf[i][j][r] += sj[j] * (float)t0[r];
      }
    __builtin_amdgcn_s_setprio(0);
    __builtin_amdgcn_s_barrier();

    // ---- phase 2: ks0, M-half 1; issue next-tile B stage ----
#pragma unroll
    for (int i = 0; i < 4; ++i)
      af[i] = *(const v4i*)&A[(wm + 64 + i * 16 + lm) * BK + o0];
    if (kt + 1 < KT) {
#pragma unroll
      for (int i = 0; i < 4; ++i)
        gload16(gB + koff + (size_t)(i * 64) * IN_,
                &Bs[cur ^ 1][i * 8192 + tid * 16]);
    }
    __builtin_amdgcn_s_barrier();
    __builtin_amdgcn_s_setprio(1);
#pragma unroll
    for (int i = 0; i < 4; ++i)
#pragma unroll
      for (int j = 0; j < 4; ++j) {
        t0 = __builtin_amdgcn_mfma_i32_16x16x64_i8(af[i], bf[j], zero4, 0, 0, 0);
#pragma unroll
        for (int r = 0; r < 4; ++r) accf[4 + i][j][r] += sj[j] * (float)t0[r];
      }
    __builtin_amdgcn_s_setprio(0);
    __builtin_amdgcn_s_barrier();

    // ---- phase 3: ks1, M-half 0 ----
    const int o1 = o0 ^ 64;
#pragma unroll
    for (int j = 0; j < 4; ++j)
      bf[j] = *(const v4i*)&Bb[(wn + j * 16 + lm) * BK + o1];
#pragma unroll
    for (int i = 0; i < 4; ++i)
      af[i] = *(const v4i*)&A[(wm + i * 16 + lm) * BK + o1];
    __builtin_amdgcn_s_barrier();
    __builtin_amdgcn_s_setprio(1);
#pragma unroll
    for (int i = 0; i < 4; ++i)
#pragma unroll
      for (int j = 0; j < 4; ++j) {
        t0 = __builtin_amdgcn_mfma_i32_16x16x64_i8(af[i], bf[j], zero4, 0, 0, 0);
#pragma unroll
        for (int r = 0; r < 4; ++r) accf[i][j][r] += sj[j] * (float)t0[r];
      }
    __builtin_amdgcn_s_setprio(0);
    __builtin_amdgcn_s_barrier();

    // ---- phase 4: ks1, M-half 1 ----
#pragma unroll
    for (int i = 0; i < 4; ++i)
      af[i] = *(const v4i*)&A[(wm + 64 + i * 16 + lm) * BK + o1];
    __builtin_amdgcn_s_barrier();
    __builtin_amdgcn_s_setprio(1);
#pragma unroll
    for (int i = 0; i < 4; ++i)
#pragma unroll
      for (int j = 0; j < 4; ++j) {
        t0 = __builtin_amdgcn_mfma_i32_16x16x64_i8(af[i], bf[j], zero4, 0, 0, 0);
#pragma unroll
        for (int r = 0; r < 4; ++r) accf[4 + i][j][r] += sj[j] * (float)t0[r];
      }
    __builtin_amdgcn_s_setprio(0);

    __syncthreads();  // tile end: vmcnt(0) drain (covered) + barrier
    cur ^= 1;
  }

  // epilogue: out = scale_t * (accf - zp_t * C1[o])
  float cj[4];
#pragma unroll
  for (int j = 0; j < 4; ++j) cj[j] = c1[C0 + wn + j * 16 + lm];
#pragma unroll
  for (int i = 0; i < 8; ++i) {
#pragma unroll
    for (int r = 0; r < 4; ++r) {
      const int row = R0 + wm + i * 16 + quad * 4 + r;
      const float tsc = tscale[row];
      const float tz = tzp[row];
#pragma unroll
      for (int j = 0; j < 4; ++j) {
        const int col = C0 + wn + j * 16 + lm;
        out[(size_t)row * OUT_ + col] = tsc * (accf[i][j][r] - tz * cj[j]);
      }
    }
  }
}

extern "C" void kernel_launch(void* const* d_in, const int* in_sizes, int n_in,
                              void* d_out, int out_size, void* d_ws, size_t ws_size,
                              hipStream_t stream) {
  const float* x = (const float*)d_in[0];
  const int* w = (const int*)d_in[1];       // int inputs materialized as int32
  const float* scales = (const float*)d_in[2];
  const float* zeros = (const float*)d_in[3];
  // d_in[4] = group_size scalar (256), baked in at compile time

  uint8_t* ws = (uint8_t*)d_ws;
  int8_t* q = (int8_t*)ws;                                  // 33,554,432 B
  int8_t* wq = (int8_t*)(ws + 33554432);                    // 16,777,216 B
  float* tscale = (float*)(ws + 33554432 + 16777216);       // 32 KB
  float* tzp = (float*)(ws + 33554432 + 16777216 + 32768);  // 32 KB
  float* c1 = (float*)(ws + 33554432 + 16777216 + 65536);   // 16 KB
  float* out = (float*)d_out;

  hipLaunchKernelGGL(quant_kernel, dim3(T_), dim3(256), 0, stream, x, q, tscale, tzp);
  hipLaunchKernelGGL(wprep_kernel, dim3(OUT_), dim3(256), 0, stream, w, scales, zeros, wq, c1);
  hipLaunchKernelGGL(gemm_kernel, dim3(GX, GY), dim3(512), 0, stream,
                     q, wq, scales, tscale, tzp, c1, out);
}

// Round 3
// 433.511 us; speedup vs baseline: 1.3204x; 1.3204x over previous
//
#include <hip/hip_runtime.h>
#include <hip/hip_bf16.h>
#include <stdint.h>

#define T_   8192   // B*S tokens
#define IN_  4096
#define OUT_ 4096
#define GS_  256
#define NG_  16

#define BM 128
#define BN 128
#define BK 128
#define KT (IN_ / BK)   // 32 K-tiles, group = 2 K-tiles

typedef int   v4i __attribute__((ext_vector_type(4)));
typedef float f4  __attribute__((ext_vector_type(4)));

__device__ __forceinline__ void gload16(const void* g, void* l) {
  __builtin_amdgcn_global_load_lds(
      (const __attribute__((address_space(1))) void*)g,
      (__attribute__((address_space(3))) void*)l, 16, 0, 0);
}

// ---------------- per-token dynamic quant ----------------------------------
// Exact divides only for scale/zp; per-element uses x*(1/scale) (rintf slack
// absorbed by the 0.615 absmax threshold; one LSB of q ~ 0.01 in the output).
__global__ __launch_bounds__(256) void quant_kernel(
    const float* __restrict__ x, int8_t* __restrict__ q,
    float* __restrict__ tscale, float* __restrict__ tzp) {
  const int t = blockIdx.x;
  const int tid = threadIdx.x;
  const float* xr = x + (size_t)t * IN_ + tid * 16;
  float vals[16];
  {
    f4 v0 = *(const f4*)(xr);
    f4 v1 = *(const f4*)(xr + 4);
    f4 v2 = *(const f4*)(xr + 8);
    f4 v3 = *(const f4*)(xr + 12);
#pragma unroll
    for (int i = 0; i < 4; ++i) {
      vals[i] = v0[i]; vals[4 + i] = v1[i]; vals[8 + i] = v2[i]; vals[12 + i] = v3[i];
    }
  }
  float mn = 0.f, mx = 0.f;   // ref clamps: min(.,0), max(.,0)
#pragma unroll
  for (int i = 0; i < 16; ++i) { mn = fminf(mn, vals[i]); mx = fmaxf(mx, vals[i]); }
#pragma unroll
  for (int off = 32; off > 0; off >>= 1) {
    mn = fminf(mn, __shfl_xor(mn, off));
    mx = fmaxf(mx, __shfl_xor(mx, off));
  }
  __shared__ float smn[4], smx[4];
  if ((tid & 63) == 0) { smn[tid >> 6] = mn; smx[tid >> 6] = mx; }
  __syncthreads();
  mn = fminf(fminf(smn[0], smn[1]), fminf(smn[2], smn[3]));
  mx = fmaxf(fmaxf(smx[0], smx[1]), fmaxf(smx[2], smx[3]));

  const float eps = 1.1920928955078125e-7f;  // np.finfo(float32).eps
  float scale = fmaxf((mx - mn) / 255.0f, eps);
  float rmn = mn / scale;   // exact divide (zp must be bit-exact)
  float rmx = mx / scale;
  float zp0 = ((-128.0f + rmn) + (127.0f + rmx) > 0.0f) ? (-128.0f - rmn)
                                                        : (127.0f - rmx);
  float zp = fminf(fmaxf(rintf(zp0), -128.0f), 127.0f);
  if (tid == 0) { tscale[t] = scale; tzp[t] = zp; }

  const float inv = 1.0f / scale;  // one exact divide; 16 multiplies below
  v4i packed;
#pragma unroll
  for (int w = 0; w < 4; ++w) {
    int word = 0;
#pragma unroll
    for (int e = 0; e < 4; ++e) {
      float qf = rintf(vals[w * 4 + e] * inv) + zp;
      qf = fminf(fmaxf(qf, -128.0f), 127.0f);
      int qi = (int)qf;
      word |= (qi & 0xff) << (8 * e);
    }
    packed[w] = word;
  }
  *(v4i*)(q + (size_t)t * IN_ + tid * 16) = packed;
}

// ---------------- weight prep: w' = w - z (int8), C1[o] = sum_g s*sum(w') ---
__global__ __launch_bounds__(256) void wprep_kernel(
    const int* __restrict__ w, const float* __restrict__ scales,
    const float* __restrict__ zeros, int8_t* __restrict__ wq,
    float* __restrict__ c1) {
  const int o = blockIdx.x;
  const int tid = threadIdx.x;
  const int g = tid >> 4;  // 16 threads per group of 256 elems
  const int* wr = w + (size_t)o * IN_ + tid * 16;
  const int zi = (int)zeros[o * NG_ + g];
  int ssum = 0;
  v4i packed;
#pragma unroll
  for (int blk = 0; blk < 4; ++blk) {
    v4i ww = *(const v4i*)(wr + blk * 4);
    int word = 0;
#pragma unroll
    for (int e = 0; e < 4; ++e) {
      int wp = ww[e] - zi;   // in [-15,15], fits int8
      ssum += wp;
      word |= (wp & 0xff) << (8 * e);
    }
    packed[blk] = word;
  }
  *(v4i*)(wq + (size_t)o * IN_ + tid * 16) = packed;
  ssum += __shfl_xor(ssum, 1);
  ssum += __shfl_xor(ssum, 2);
  ssum += __shfl_xor(ssum, 4);
  ssum += __shfl_xor(ssum, 8);
  __shared__ float part[NG_];
  if ((tid & 15) == 0) part[g] = scales[o * NG_ + g] * (float)ssum;
  __syncthreads();
  if (tid == 0) {
    float s = 0.f;
#pragma unroll
    for (int i = 0; i < NG_; ++i) s += part[i];
    c1[o] = s;
  }
}

// ---------------- int8 groupwise GEMM, BK=128, dbuf prefetch ----------------
// Round-0 structure (128x128, 4 waves, 64x64/wave, 16x16x64 MFMA, group-
// boundary folds, 2 blocks/CU) with ONE change: LDS tiles double-buffered
// (72 KB total, still 2 blocks/CU) and tile kt+1's global_load_lds issued at
// the TOP of iteration kt.  The single end-of-iteration __syncthreads then
// drains vmcnt(0) one full compute phase (~650-1100 cy) after issue instead
// of immediately after -> load latency hidden instead of exposed (T3-lite).
// Also drops from 2 barriers/kt to 1.  Compute + epilogue byte-identical to
// the verified round-0 kernel.
// LDS layout per buffer: row-major [128][BK]; 16-B chunk q of row r stored at
// physical chunk q ^ (r&7).  Staging swizzles the GLOBAL column instead
// (global_load_lds requires contiguous lane->LDS).  Fragment reads then hit
// 8 distinct bank-quads per 16 lanes -> 2-way conflicts only (free, m136).
__global__ __launch_bounds__(256, 2) void gemm_kernel(
    const int8_t* __restrict__ q, const int8_t* __restrict__ wq,
    const float* __restrict__ scales, const float* __restrict__ tscale,
    const float* __restrict__ tzp, const float* __restrict__ c1,
    float* __restrict__ out) {
  __shared__ int8_t As[2][BM * BK];   // 2 x 16 KB
  __shared__ int8_t Bs[2][BN * BK];   // 2 x 16 KB
  __shared__ float sSc[NG_ * BN];     // 8 KB   (72 KB total -> 2 blocks/CU)

  const int tid = threadIdx.x;
  const int lane = tid & 63;
  const int wid = tid >> 6;
  const int R0 = blockIdx.y * BM;
  const int C0 = blockIdx.x * BN;

  // stage this block's scales: sSc[g][col_local]
#pragma unroll
  for (int e = 0; e < 8; ++e) {
    int idx = tid + e * 256;
    int oc = idx >> 4, g = idx & 15;
    sSc[g * BN + oc] = scales[(size_t)(C0 + oc) * NG_ + g];
  }

  // staging: thread covers 16 B; row = tid>>3 (+32 per i), physical chunk tid&7
  const int rA = tid >> 3;                       // 0..31
  const int cswz = ((tid & 7) ^ (rA & 7)) * 16;  // swizzled global column
  const int8_t* gA = q + (size_t)(R0 + rA) * IN_ + cswz;
  const int8_t* gB = wq + (size_t)(C0 + rA) * IN_ + cswz;

  const int wm = (wid >> 1) * 64;
  const int wn = (wid & 1) * 64;
  const int lm = lane & 15;
  const int quad = lane >> 4;
  // fragment read offsets: logical chunk (ks*4+quad) ^ (lm&7)
  const int o0 = ((quad ^ (lm & 7)) * 16);       // ks=0
  const int aRow = (wm + lm) * BK;
  const int bRow = (wn + lm) * BK;

  v4i acci[4][4];
  float accf[4][4][4];
#pragma unroll
  for (int i = 0; i < 4; ++i)
#pragma unroll
    for (int j = 0; j < 4; ++j) {
      acci[i][j] = (v4i){0, 0, 0, 0};
#pragma unroll
      for (int r = 0; r < 4; ++r) accf[i][j][r] = 0.f;
    }

  // prologue: stage tile 0 into buffer 0
#pragma unroll
  for (int i = 0; i < 4; ++i) {
    gload16(gA + (size_t)(i * 32) * IN_, &As[0][i * 4096 + tid * 16]);
    gload16(gB + (size_t)(i * 32) * IN_, &Bs[0][i * 4096 + tid * 16]);
  }
  __syncthreads();   // drains vmcnt (tile 0 resident); also covers sSc writes

  int cur = 0;
  for (int kt = 0; kt < KT; ++kt) {
    // prefetch tile kt+1 into the other buffer (drained by end-of-kt sync;
    // buffer was last read at kt-1, protected by end-of-(kt-1) sync)
    if (kt + 1 < KT) {
      const size_t koff = (size_t)(kt + 1) * BK;
#pragma unroll
      for (int i = 0; i < 4; ++i) {
        gload16(gA + koff + (size_t)(i * 32) * IN_,
                &As[cur ^ 1][i * 4096 + tid * 16]);
        gload16(gB + koff + (size_t)(i * 32) * IN_,
                &Bs[cur ^ 1][i * 4096 + tid * 16]);
      }
    }

#pragma unroll
    for (int ks = 0; ks < 2; ++ks) {
      const int co = o0 ^ (ks * 64);   // chunk offset for this k-step
      v4i af[4], bf[4];
#pragma unroll
      for (int i = 0; i < 4; ++i)
        af[i] = *(const v4i*)&As[cur][aRow + i * (16 * BK) + co];
#pragma unroll
      for (int j = 0; j < 4; ++j)
        bf[j] = *(const v4i*)&Bs[cur][bRow + j * (16 * BK) + co];
#pragma unroll
      for (int i = 0; i < 4; ++i)
#pragma unroll
        for (int j = 0; j < 4; ++j)
          acci[i][j] =
              __builtin_amdgcn_mfma_i32_16x16x64_i8(af[i], bf[j], acci[i][j], 0, 0, 0);
    }

    if (kt & 1) {  // group boundary (group = 2 kt): fold int acc into fp32
      const int g = kt >> 1;
      float sj[4];
#pragma unroll
      for (int j = 0; j < 4; ++j) sj[j] = sSc[g * BN + wn + j * 16 + lm];
#pragma unroll
      for (int i = 0; i < 4; ++i)
#pragma unroll
        for (int j = 0; j < 4; ++j) {
#pragma unroll
          for (int r = 0; r < 4; ++r)
            accf[i][j][r] += sj[j] * (float)acci[i][j][r];
          acci[i][j] = (v4i){0, 0, 0, 0};
        }
    }

    __syncthreads();  // vmcnt(0)+barrier: prefetched tile resident, cur reads done
    cur ^= 1;
  }

  // epilogue: out = scale_t * (accf - zp_t * C1[o])
  float cj[4];
#pragma unroll
  for (int j = 0; j < 4; ++j) cj[j] = c1[C0 + wn + j * 16 + lm];
#pragma unroll
  for (int i = 0; i < 4; ++i) {
#pragma unroll
    for (int r = 0; r < 4; ++r) {
      const int row = R0 + wm + i * 16 + quad * 4 + r;
      const float tsc = tscale[row];
      const float tz = tzp[row];
#pragma unroll
      for (int j = 0; j < 4; ++j) {
        const int col = C0 + wn + j * 16 + lm;
        out[(size_t)row * OUT_ + col] = tsc * (accf[i][j][r] - tz * cj[j]);
      }
    }
  }
}

extern "C" void kernel_launch(void* const* d_in, const int* in_sizes, int n_in,
                              void* d_out, int out_size, void* d_ws, size_t ws_size,
                              hipStream_t stream) {
  const float* x = (const float*)d_in[0];
  const int* w = (const int*)d_in[1];       // int inputs materialized as int32
  const float* scales = (const float*)d_in[2];
  const float* zeros = (const float*)d_in[3];
  // d_in[4] = group_size scalar (256), baked in at compile time

  uint8_t* ws = (uint8_t*)d_ws;
  int8_t* q = (int8_t*)ws;                                  // 33,554,432 B
  int8_t* wq = (int8_t*)(ws + 33554432);                    // 16,777,216 B
  float* tscale = (float*)(ws + 33554432 + 16777216);       // 32 KB
  float* tzp = (float*)(ws + 33554432 + 16777216 + 32768);  // 32 KB
  float* c1 = (float*)(ws + 33554432 + 16777216 + 65536);   // 16 KB
  float* out = (float*)d_out;

  hipLaunchKernelGGL(quant_kernel, dim3(T_), dim3(256), 0, stream, x, q, tscale, tzp);
  hipLaunchKernelGGL(wprep_kernel, dim3(OUT_), dim3(256), 0, stream, w, scales, zeros, wq, c1);
  hipLaunchKernelGGL(gemm_kernel, dim3(OUT_ / BN, T_ / BM), dim3(256), 0, stream,
                     q, wq, scales, tscale, tzp, c1, out);
}